// Round 6
// baseline (229.706 us; speedup 1.0000x reference)
//
#include <hip/hip_runtime.h>
#include <hip/hip_bf16.h>

typedef float    f4    __attribute__((ext_vector_type(4)));
typedef short    s8v   __attribute__((ext_vector_type(8)));
typedef __bf16   bf8v  __attribute__((ext_vector_type(8)));
typedef unsigned int u32x4v __attribute__((ext_vector_type(4)));
typedef unsigned short u16;

typedef const __attribute__((address_space(1))) void GAS;
typedef __attribute__((address_space(3))) void LAS;

#define NB 8
#define NN 256
#define ND 128

static __device__ __forceinline__ u16 f2bf(float f) {
    union { float f; unsigned u; } v; v.f = f;
    unsigned r = v.u + 0x7FFF + ((v.u >> 16) & 1);   // RNE
    return (u16)(r >> 16);
}

// pack two f32 -> two bf16 (round-half-up via +0x8000, then v_perm pack)
static __device__ __forceinline__ unsigned pack2bf(float a, float b) {
    unsigned ua = __builtin_bit_cast(unsigned, a) + 0x8000u;
    unsigned ub = __builtin_bit_cast(unsigned, b) + 0x8000u;
    return __builtin_amdgcn_perm(ub, ua, 0x07060302u);  // {ua[31:16], ub[31:16]<<16}
}

// ---------------- precompute: P = x@W1a + b1m, Qt[b][d][j] = (x@W1b)[d], pack W1c frags
__global__ __launch_bounds__(256) void prep_kernel(
    const float* __restrict__ x, const float* __restrict__ W1m,
    const float* __restrict__ b1m,
    float* __restrict__ P, float* __restrict__ Qt, u16* __restrict__ W1cp)
{
    if (blockIdx.x == 1024) {
        // pack W1c (rows 256..383 of W1m) into MFMA B-fragment order:
        // frag[(kt*8+nt)*64 + lane][t] = W1c[kt*32 + (lane>>4)*8 + t][nt*16 + (lane&15)]
        for (int idx = threadIdx.x; idx < 16384; idx += 256) {
            int e  = idx & 7;
            int ln = (idx >> 3) & 63;
            int nt = (idx >> 9) & 7;
            int kt = idx >> 12;
            int k  = kt * 32 + (ln >> 4) * 8 + e;
            int d  = nt * 16 + (ln & 15);
            W1cp[idx] = f2bf(W1m[(2 * ND + k) * ND + d]);
        }
        return;
    }
    __shared__ float xl[256];
    int t = threadIdx.x;
    int row0 = blockIdx.x * 2;
    xl[t] = x[row0 * ND + t];
    __syncthreads();
    int r = t >> 7;            // 0..1
    int d = t & 127;
    int row = row0 + r;
    float sp = b1m[d], sq = 0.f;
    const float* xr = &xl[r * ND];
    #pragma unroll 8
    for (int k = 0; k < ND; ++k) {
        float xv = xr[k];
        sp += xv * W1m[k * ND + d];
        sq += xv * W1m[(ND + k) * ND + d];
    }
    P[row * ND + d] = sp;
    Qt[((size_t)((row >> 8) * ND + d)) * NN + (row & 255)] = sq;
}

// ---------------- fused: wave-autonomous. Each wave owns 64 j-rows of (b,i):
// stages its own 16-row tiles (dbuf, global_load_lds), computes all 128 cols,
// masked-aggregates in registers. Barriers only for the final reduction+tail.
__global__ __launch_bounds__(256, 2) void fused_kernel(
    const float* __restrict__ x, const float* __restrict__ edge0,
    const int* __restrict__ mask,
    const float* __restrict__ W2m, const float* __restrict__ b2m,
    const float* __restrict__ W1u, const float* __restrict__ b1u,
    const float* __restrict__ W2u, const float* __restrict__ b2u,
    const float* __restrict__ gamma, const float* __restrict__ beta,
    const float* __restrict__ P, const float* __restrict__ Qt,
    const u16* __restrict__ W1cp,
    float* __restrict__ out)
{
    __shared__ float ebuf[4][2][2048];   // per-wave private 2 x 8KB tiles (64KB)
    __shared__ float ml[NN];
    __shared__ float xrow[ND];
    __shared__ float redc[4], redA[4], redB[4];

    // bijective XCD swizzle: XCD k owns batch k (Qt/P slabs XCD-L2-local)
    const int bid  = (blockIdx.x & 7) * 256 + (blockIdx.x >> 3);
    const int b    = bid >> 8;
    const int tid  = threadIdx.x;
    const int wave = tid >> 6;
    const int lane = tid & 63;
    const int l15  = lane & 15;
    const int lg   = lane >> 4;

    // wave's 64 rows start at j = wave*64
    const char* e0c = (const char*)(edge0 + (size_t)bid * (NN * ND))
                    + (size_t)wave * 64 * 512;

    float mval = (float)mask[bid * NN + tid];
    ml[tid] = mval;
    if (tid < ND) xrow[tid] = x[bid * ND + tid];

    // B fragments: ALL 8 col-tiles x 4 k-tiles (128 VGPR, loop-invariant)
    s8v bfr[4][8];
    #pragma unroll
    for (int kt = 0; kt < 4; ++kt)
        #pragma unroll
        for (int nt = 0; nt < 8; ++nt)
            bfr[kt][nt] = *reinterpret_cast<const s8v*>(
                &W1cp[(((kt * 8) + nt) * 64 + lane) * 8]);

    // P per col-tile
    float pv[8];
    #pragma unroll
    for (int nt = 0; nt < 8; ++nt) pv[nt] = P[bid * ND + nt * 16 + l15];

    // Q base: Qt[b][col][j], col = nt*16+l15, j = wave*64 + t*16 + lg*4
    const float* qb = Qt + ((size_t)b * ND + l15) * NN + wave * 64 + lg * 4;

    float agg[8] = {0.f, 0.f, 0.f, 0.f, 0.f, 0.f, 0.f, 0.f};

    // stage 16-row tile t into private buffer bb (LDS linear, source XOR-swizzled)
    auto STAGE = [&](int t, int bb) {
        const char* cb = e0c + (size_t)t * 8192;
        #pragma unroll
        for (int u = 0; u < 8; ++u) {
            int row  = u * 2 + (lane >> 5);
            int colb = (lane & 31) * 16;
            const char* g = cb + row * 512 + (colb ^ ((row & 7) << 4));
            __builtin_amdgcn_global_load_lds(
                (GAS*)g, (LAS*)&ebuf[wave][bb][u * 256], 16, 0, 0);
        }
    };

    // zero the vmcnt ledger (prologue loads: bfr, pv, mask, xrow)
    asm volatile("s_waitcnt vmcnt(0) lgkmcnt(0)" ::: "memory");
    __builtin_amdgcn_sched_barrier(0);
    STAGE(0, 0);
    __builtin_amdgcn_sched_barrier(0);

    #pragma unroll
    for (int t = 0; t < 4; ++t) {
        const int pb = t & 1;
        // issue Q loads for tile t (8 f4)
        f4 qv[8];
        #pragma unroll
        for (int nt = 0; nt < 8; ++nt)
            qv[nt] = *reinterpret_cast<const f4*>(qb + nt * 4096 + t * 16);
        __builtin_amdgcn_sched_barrier(0);
        // issue next stage; counted wait drains exactly stage_t + Q_t
        if (t < 3) {
            STAGE(t + 1, pb ^ 1);
            __builtin_amdgcn_sched_barrier(0);
            asm volatile("s_waitcnt vmcnt(8)" ::: "memory");   // leaves stage_{t+1}
        } else {
            asm volatile("s_waitcnt vmcnt(0)" ::: "memory");
        }
        __builtin_amdgcn_sched_barrier(0);

        // mask for this tile's 4 rows (per lg group)
        f4 mk = *reinterpret_cast<const f4*>(&ml[wave * 64 + t * 16 + lg * 4]);

        // A: 16 rows x 128 k from private LDS, f32 -> packed bf16 frags
        const char* bufc = (const char*)&ebuf[wave][pb][0];
        const int rb  = l15 * 512;
        const int swz = (l15 & 7) << 4;
        s8v apk[4];
        #pragma unroll
        for (int kt = 0; kt < 4; ++kt) {
            int cbyte = kt * 128 + lg * 32;
            f4 a0 = *reinterpret_cast<const f4*>(bufc + rb + ((cbyte)      ^ swz));
            f4 a1 = *reinterpret_cast<const f4*>(bufc + rb + ((cbyte + 16) ^ swz));
            u32x4v aw;
            aw[0] = pack2bf(a0[0], a0[1]);
            aw[1] = pack2bf(a0[2], a0[3]);
            aw[2] = pack2bf(a1[0], a1[1]);
            aw[3] = pack2bf(a1[2], a1[3]);
            apk[kt] = __builtin_bit_cast(s8v, aw);
        }
        // all 128 cols for these 16 rows: 8 nt x 4 kt MFMA, agg immediately
        #pragma unroll
        for (int nt = 0; nt < 8; ++nt) {
            f4 acc = {0.f, 0.f, 0.f, 0.f};
            #pragma unroll
            for (int kt = 0; kt < 4; ++kt)
                acc = __builtin_amdgcn_mfma_f32_16x16x32_bf16(
                    __builtin_bit_cast(bf8v, apk[kt]),
                    __builtin_bit_cast(bf8v, bfr[kt][nt]), acc, 0, 0, 0);
            #pragma unroll
            for (int r = 0; r < 4; ++r) {
                float h = fmaxf(acc[r] + pv[nt] + qv[nt][r], 0.f);
                agg[nt] += mk[r] * h;
            }
        }
    }

    // per-wave column sums -> wave's dead buffer 0 region
    #pragma unroll
    for (int nt = 0; nt < 8; ++nt) {
        float a = agg[nt];
        a += __shfl_xor(a, 16);
        a += __shfl_xor(a, 32);
        if (lg == 0) ebuf[wave][0][nt * 16 + l15] = a;
    }
    // cnt = sum(mask)
    float cv = mval;
    #pragma unroll
    for (int o = 32; o > 0; o >>= 1) cv += __shfl_xor(cv, o);
    if (lane == 0) redc[wave] = cv;
    __syncthreads();

    // tail scratch carved from dead LDS
    float* aggH = &ebuf[0][1][1024];
    float* am   = &ebuf[1][1][1024];
    float* hu   = &ebuf[2][1][1024];
    float* yl   = &ebuf[3][1][1024];

    const float cnt = redc[0] + redc[1] + redc[2] + redc[3];
    const float inv = 1.f / (cnt + 1e-6f);
    const int d  = tid & 127;
    const int hf = tid >> 7;

    if (tid < ND)
        aggH[tid] = ebuf[0][0][tid] + ebuf[1][0][tid] + ebuf[2][0][tid] + ebuf[3][0][tid];
    __syncthreads();

    // agg_msg = (aggH @ W2m + cnt*b2m) / (cnt+eps)   [K split across 2 thread halves]
    {
        float s = 0.f;
        #pragma unroll 8
        for (int k = hf * 64; k < hf * 64 + 64; ++k) s += aggH[k] * W2m[k * ND + d];
        ml[tid] = s;
    }
    __syncthreads();
    if (tid < ND) am[d] = (ml[d] + ml[d + ND] + cnt * b2m[d]) * inv;
    __syncthreads();
    // hu = relu([x, agg] @ W1u + b1u)   [half 0: x part, half 1: agg part]
    {
        float s = 0.f;
        const float* W = W1u + (size_t)hf * ND * ND;
        const float* v = hf ? am : xrow;
        #pragma unroll 8
        for (int k = 0; k < ND; ++k) s += v[k] * W[k * ND + d];
        ml[tid] = s;
    }
    __syncthreads();
    if (tid < ND) hu[d] = fmaxf(ml[d] + ml[d + ND] + b1u[d], 0.f);
    __syncthreads();
    // y = x + hu @ W2u + b2u   [K split across 2 thread halves]
    {
        float s = 0.f;
        #pragma unroll 8
        for (int k = hf * 64; k < hf * 64 + 64; ++k) s += hu[k] * W2u[k * ND + d];
        ml[tid] = s;
    }
    __syncthreads();
    if (tid < ND) yl[d] = xrow[d] + ml[d] + ml[d + ND] + b2u[d];
    __syncthreads();
    // LayerNorm over the 128 dims
    float yv = (tid < ND) ? yl[tid] : 0.f;
    float s1 = yv, s2 = yv * yv;
    #pragma unroll
    for (int o = 32; o > 0; o >>= 1) { s1 += __shfl_xor(s1, o); s2 += __shfl_xor(s2, o); }
    if (lane == 0) { redA[wave] = s1; redB[wave] = s2; }
    __syncthreads();
    if (tid < ND) {
        float mu  = (redA[0] + redA[1] + redA[2] + redA[3]) * (1.f / 128.f);
        float ex2 = (redB[0] + redB[1] + redB[2] + redB[3]) * (1.f / 128.f);
        float var = ex2 - mu * mu;
        float rs  = rsqrtf(var + 1e-5f);
        out[bid * ND + d] = (yl[d] - mu) * rs * gamma[d] + beta[d];
    }
}

extern "C" void kernel_launch(void* const* d_in, const int* in_sizes, int n_in,
                              void* d_out, int out_size, void* d_ws, size_t ws_size,
                              hipStream_t stream) {
    (void)in_sizes; (void)n_in; (void)out_size; (void)ws_size;
    const float* x     = (const float*)d_in[0];
    const float* edge0 = (const float*)d_in[1];
    const int*   mask  = (const int*)d_in[2];
    const float* W1m   = (const float*)d_in[3];
    const float* b1m   = (const float*)d_in[4];
    const float* W2m   = (const float*)d_in[5];
    const float* b2m   = (const float*)d_in[6];
    const float* W1u   = (const float*)d_in[7];
    const float* b1u   = (const float*)d_in[8];
    const float* W2u   = (const float*)d_in[9];
    const float* b2u   = (const float*)d_in[10];
    const float* gamma = (const float*)d_in[11];
    const float* beta  = (const float*)d_in[12];

    float* P    = (float*)d_ws;                 // 2048*128 f32 = 1 MB
    float* Qt   = P + 2048 * 128;               // 8*128*256 f32 = 1 MB
    u16*   W1cp = (u16*)(Qt + 8 * 128 * 256);   // 16384 bf16 = 32 KB

    float* o = (float*)d_out;

    prep_kernel<<<dim3(1025), dim3(256), 0, stream>>>(x, W1m, b1m, P, Qt, W1cp);
    fused_kernel<<<dim3(2048), dim3(256), 0, stream>>>(
        x, edge0, mask, W2m, b2m, W1u, b1u, W2u, b2u, gamma, beta,
        P, Qt, W1cp, o);
}

// Round 7
// 193.425 us; speedup vs baseline: 1.1876x; 1.1876x over previous
//
#include <hip/hip_runtime.h>
#include <hip/hip_bf16.h>

typedef float    f4    __attribute__((ext_vector_type(4)));
typedef short    s8v   __attribute__((ext_vector_type(8)));
typedef __bf16   bf8v  __attribute__((ext_vector_type(8)));
typedef unsigned int u32x4v __attribute__((ext_vector_type(4)));
typedef unsigned short u16;

#define NB 8
#define NN 256
#define ND 128

static __device__ __forceinline__ u16 f2bf(float f) {
    union { float f; unsigned u; } v; v.f = f;
    unsigned r = v.u + 0x7FFF + ((v.u >> 16) & 1);   // RNE
    return (u16)(r >> 16);
}

// pack two f32 -> two bf16 (round-half-up via +0x8000, then v_perm pack)
static __device__ __forceinline__ unsigned pack2bf(float a, float b) {
    unsigned ua = __builtin_bit_cast(unsigned, a) + 0x8000u;
    unsigned ub = __builtin_bit_cast(unsigned, b) + 0x8000u;
    return __builtin_amdgcn_perm(ub, ua, 0x07060302u);  // {ua[31:16], ub[31:16]<<16}
}

// ---------------- precompute: P = x@W1a + b1m, Qt[b][d][j] = (x@W1b)[d], pack W1c frags
__global__ __launch_bounds__(256) void prep_kernel(
    const float* __restrict__ x, const float* __restrict__ W1m,
    const float* __restrict__ b1m,
    float* __restrict__ P, float* __restrict__ Qt, u16* __restrict__ W1cp)
{
    if (blockIdx.x == 1024) {
        // pack W1c (rows 256..383 of W1m) into MFMA B-fragment order:
        // frag[(kt*8+nt)*64 + lane][t] = W1c[kt*32 + (lane>>4)*8 + t][nt*16 + (lane&15)]
        for (int idx = threadIdx.x; idx < 16384; idx += 256) {
            int e  = idx & 7;
            int ln = (idx >> 3) & 63;
            int nt = (idx >> 9) & 7;
            int kt = idx >> 12;
            int k  = kt * 32 + (ln >> 4) * 8 + e;
            int d  = nt * 16 + (ln & 15);
            W1cp[idx] = f2bf(W1m[(2 * ND + k) * ND + d]);
        }
        return;
    }
    __shared__ float xl[256];
    int t = threadIdx.x;
    int row0 = blockIdx.x * 2;
    xl[t] = x[row0 * ND + t];
    __syncthreads();
    int r = t >> 7;            // 0..1
    int d = t & 127;
    int row = row0 + r;
    float sp = b1m[d], sq = 0.f;
    const float* xr = &xl[r * ND];
    #pragma unroll 8
    for (int k = 0; k < ND; ++k) {
        float xv = xr[k];
        sp += xv * W1m[k * ND + d];
        sq += xv * W1m[(ND + k) * ND + d];
    }
    P[row * ND + d] = sp;
    Qt[((size_t)((row >> 8) * ND + d)) * NN + (row & 255)] = sq;
}

// ---------------- fused: per-block (b,i). Each wave owns 32 output cols and
// streams ALL 256 j-rows global->register as MFMA A-fragments (no LDS staging,
// no main-loop barriers). Masked agg in registers; tail after one barrier.
__global__ __launch_bounds__(256, 2) void fused_kernel(
    const float* __restrict__ x, const float* __restrict__ edge0,
    const int* __restrict__ mask,
    const float* __restrict__ W2m, const float* __restrict__ b2m,
    const float* __restrict__ W1u, const float* __restrict__ b1u,
    const float* __restrict__ W2u, const float* __restrict__ b2u,
    const float* __restrict__ gamma, const float* __restrict__ beta,
    const float* __restrict__ P, const float* __restrict__ Qt,
    const u16* __restrict__ W1cp,
    float* __restrict__ out)
{
    __shared__ float ml[NN];
    __shared__ float xrow[ND];
    __shared__ float aggH[ND], am[ND], hu[ND], yl[ND];
    __shared__ float redc[4], redA[4], redB[4];

    // bijective XCD swizzle: XCD k owns batch k (P/Qt/x slabs XCD-L2-local)
    const int bid  = (blockIdx.x & 7) * 256 + (blockIdx.x >> 3);
    const int b    = bid >> 8;
    const int tid  = threadIdx.x;
    const int wave = tid >> 6;
    const int lane = tid & 63;
    const int l15  = lane & 15;
    const int lg   = lane >> 4;

    const char* e0c = (const char*)(edge0 + (size_t)bid * (NN * ND));
    // this lane's A-frag row base (row j indexed by l15 within a tile)
    const char* erow = e0c + l15 * 512 + lg * 32;

    float mval = (float)mask[bid * NN + tid];
    ml[tid] = mval;
    if (tid < ND) xrow[tid] = x[bid * ND + tid];

    // B fragments: this wave's 2 col-tiles x 4 k-tiles (32 VGPR)
    s8v bfr[4][2];
    #pragma unroll
    for (int kt = 0; kt < 4; ++kt)
        #pragma unroll
        for (int n = 0; n < 2; ++n)
            bfr[kt][n] = *reinterpret_cast<const s8v*>(
                &W1cp[(((kt * 8) + (wave * 2 + n)) * 64 + lane) * 8]);

    const int col0 = wave * 32 + l15;
    const float pv0 = P[bid * ND + col0];
    const float pv1 = P[bid * ND + col0 + 16];
    const float* qt0 = Qt + (size_t)(b * ND + col0) * NN + lg * 4;
    const float* qt1 = qt0 + (size_t)16 * NN;

    float agg0 = 0.f, agg1 = 0.f;

    // drain prologue VMEM + make ml/xrow visible; ledger = 0 after this
    __syncthreads();

    f4 eA[2][8];   // double-buffered raw edge rows (static indexing via unroll)
    f4 qA[2][2];

    // issue group 0 (tile 0): 2 Q + 8 E = 10 VMEM
    {
        qA[0][0] = *reinterpret_cast<const f4*>(qt0);
        qA[0][1] = *reinterpret_cast<const f4*>(qt1);
        #pragma unroll
        for (int kt = 0; kt < 4; ++kt) {
            eA[0][2 * kt]     = *reinterpret_cast<const f4*>(erow + kt * 128);
            eA[0][2 * kt + 1] = *reinterpret_cast<const f4*>(erow + kt * 128 + 16);
        }
    }
    __builtin_amdgcn_sched_barrier(0);

    #pragma unroll
    for (int t = 0; t < 16; ++t) {
        const int cur = t & 1, nxt = cur ^ 1;
        if (t < 15) {
            // issue group t+1 (10 VMEM)
            const char* er = erow + (size_t)(t + 1) * 8192;
            qA[nxt][0] = *reinterpret_cast<const f4*>(qt0 + (t + 1) * 16);
            qA[nxt][1] = *reinterpret_cast<const f4*>(qt1 + (t + 1) * 16);
            #pragma unroll
            for (int kt = 0; kt < 4; ++kt) {
                eA[nxt][2 * kt]     = *reinterpret_cast<const f4*>(er + kt * 128);
                eA[nxt][2 * kt + 1] = *reinterpret_cast<const f4*>(er + kt * 128 + 16);
            }
            __builtin_amdgcn_sched_barrier(0);
            asm volatile("s_waitcnt vmcnt(10)" ::: "memory");  // drain exactly tile t
        } else {
            __builtin_amdgcn_sched_barrier(0);
            asm volatile("s_waitcnt vmcnt(0)" ::: "memory");
        }
        __builtin_amdgcn_sched_barrier(0);

        // pack tile t: f32 -> bf16 A-fragments
        s8v apk[4];
        #pragma unroll
        for (int kt = 0; kt < 4; ++kt) {
            f4 a0 = eA[cur][2 * kt];
            f4 a1 = eA[cur][2 * kt + 1];
            u32x4v aw;
            aw[0] = pack2bf(a0[0], a0[1]);
            aw[1] = pack2bf(a0[2], a0[3]);
            aw[2] = pack2bf(a1[0], a1[1]);
            aw[3] = pack2bf(a1[2], a1[3]);
            apk[kt] = __builtin_bit_cast(s8v, aw);
        }
        // 16x16 @ 16x32 for the wave's 2 col-tiles
        f4 acc0 = {0.f, 0.f, 0.f, 0.f};
        f4 acc1 = {0.f, 0.f, 0.f, 0.f};
        #pragma unroll
        for (int kt = 0; kt < 4; ++kt) {
            acc0 = __builtin_amdgcn_mfma_f32_16x16x32_bf16(
                __builtin_bit_cast(bf8v, apk[kt]), __builtin_bit_cast(bf8v, bfr[kt][0]), acc0, 0, 0, 0);
            acc1 = __builtin_amdgcn_mfma_f32_16x16x32_bf16(
                __builtin_bit_cast(bf8v, apk[kt]), __builtin_bit_cast(bf8v, bfr[kt][1]), acc1, 0, 0, 0);
        }
        // rows j = t*16 + lg*4 + r (C/D layout); mask + relu + agg
        f4 mk = *reinterpret_cast<const f4*>(&ml[t * 16 + lg * 4]);
        f4 q0 = qA[cur][0];
        f4 q1 = qA[cur][1];
        #pragma unroll
        for (int r = 0; r < 4; ++r) {
            float h0 = fmaxf(acc0[r] + pv0 + q0[r], 0.f);
            float h1 = fmaxf(acc1[r] + pv1 + q1[r], 0.f);
            agg0 += mk[r] * h0;
            agg1 += mk[r] * h1;
        }
    }

    // reduce agg partials across the 4 row-groups (lanes l, l+16, l+32, l+48)
    agg0 += __shfl_xor(agg0, 16); agg0 += __shfl_xor(agg0, 32);
    agg1 += __shfl_xor(agg1, 16); agg1 += __shfl_xor(agg1, 32);
    if (lg == 0) {
        aggH[wave * 32 + l15]      = agg0;
        aggH[wave * 32 + 16 + l15] = agg1;
    }
    // cnt = sum(mask)
    float cv = mval;
    #pragma unroll
    for (int o = 32; o > 0; o >>= 1) cv += __shfl_xor(cv, o);
    if (lane == 0) redc[wave] = cv;
    __syncthreads();

    const float cnt = redc[0] + redc[1] + redc[2] + redc[3];
    const float inv = 1.f / (cnt + 1e-6f);
    const int d  = tid & 127;
    const int hf = tid >> 7;

    // agg_msg = (aggH @ W2m + cnt*b2m) / (cnt+eps)   [K split across 2 thread halves]
    {
        float s = 0.f;
        #pragma unroll 8
        for (int k = hf * 64; k < hf * 64 + 64; ++k) s += aggH[k] * W2m[k * ND + d];
        ml[tid] = s;
    }
    __syncthreads();
    if (tid < ND) am[d] = (ml[d] + ml[d + ND] + cnt * b2m[d]) * inv;
    __syncthreads();
    // hu = relu([x, agg] @ W1u + b1u)   [half 0: x part, half 1: agg part]
    {
        float s = 0.f;
        const float* W = W1u + (size_t)hf * ND * ND;
        const float* v = hf ? am : xrow;
        #pragma unroll 8
        for (int k = 0; k < ND; ++k) s += v[k] * W[k * ND + d];
        ml[tid] = s;
    }
    __syncthreads();
    if (tid < ND) hu[d] = fmaxf(ml[d] + ml[d + ND] + b1u[d], 0.f);
    __syncthreads();
    // y = x + hu @ W2u + b2u   [K split across 2 thread halves]
    {
        float s = 0.f;
        #pragma unroll 8
        for (int k = hf * 64; k < hf * 64 + 64; ++k) s += hu[k] * W2u[k * ND + d];
        ml[tid] = s;
    }
    __syncthreads();
    if (tid < ND) yl[d] = xrow[d] + ml[d] + ml[d + ND] + b2u[d];
    __syncthreads();
    // LayerNorm over the 128 dims
    float yv = (tid < ND) ? yl[tid] : 0.f;
    float s1 = yv, s2 = yv * yv;
    #pragma unroll
    for (int o = 32; o > 0; o >>= 1) { s1 += __shfl_xor(s1, o); s2 += __shfl_xor(s2, o); }
    if (lane == 0) { redA[wave] = s1; redB[wave] = s2; }
    __syncthreads();
    if (tid < ND) {
        float mu  = (redA[0] + redA[1] + redA[2] + redA[3]) * (1.f / 128.f);
        float ex2 = (redB[0] + redB[1] + redB[2] + redB[3]) * (1.f / 128.f);
        float var = ex2 - mu * mu;
        float rs  = rsqrtf(var + 1e-5f);
        out[bid * ND + d] = (yl[d] - mu) * rs * gamma[d] + beta[d];
    }
}

extern "C" void kernel_launch(void* const* d_in, const int* in_sizes, int n_in,
                              void* d_out, int out_size, void* d_ws, size_t ws_size,
                              hipStream_t stream) {
    (void)in_sizes; (void)n_in; (void)out_size; (void)ws_size;
    const float* x     = (const float*)d_in[0];
    const float* edge0 = (const float*)d_in[1];
    const int*   mask  = (const int*)d_in[2];
    const float* W1m   = (const float*)d_in[3];
    const float* b1m   = (const float*)d_in[4];
    const float* W2m   = (const float*)d_in[5];
    const float* b2m   = (const float*)d_in[6];
    const float* W1u   = (const float*)d_in[7];
    const float* b1u   = (const float*)d_in[8];
    const float* W2u   = (const float*)d_in[9];
    const float* b2u   = (const float*)d_in[10];
    const float* gamma = (const float*)d_in[11];
    const float* beta  = (const float*)d_in[12];

    float* P    = (float*)d_ws;                 // 2048*128 f32 = 1 MB
    float* Qt   = P + 2048 * 128;               // 8*128*256 f32 = 1 MB
    u16*   W1cp = (u16*)(Qt + 8 * 128 * 256);   // 16384 bf16 = 32 KB

    float* o = (float*)d_out;

    prep_kernel<<<dim3(1025), dim3(256), 0, stream>>>(x, W1m, b1m, P, Qt, W1cp);
    fused_kernel<<<dim3(2048), dim3(256), 0, stream>>>(
        x, edge0, mask, W2m, b2m, W1u, b1u, W2u, b2u, gamma, beta,
        P, Qt, W1cp, o);
}

// Round 8
// 95.597 us; speedup vs baseline: 2.4029x; 2.0233x over previous
//
#include <hip/hip_runtime.h>
#include <hip/hip_bf16.h>

typedef float    f4    __attribute__((ext_vector_type(4)));
typedef short    s8v   __attribute__((ext_vector_type(8)));
typedef __bf16   bf8v  __attribute__((ext_vector_type(8)));
typedef unsigned int u32x4v __attribute__((ext_vector_type(4)));
typedef unsigned short u16;

typedef const __attribute__((address_space(1))) void GAS;
typedef __attribute__((address_space(3))) void LAS;

#define NB 8
#define NN 256
#define ND 128

static __device__ __forceinline__ u16 f2bf(float f) {
    union { float f; unsigned u; } v; v.f = f;
    unsigned r = v.u + 0x7FFF + ((v.u >> 16) & 1);   // RNE
    return (u16)(r >> 16);
}

// pack two f32 -> two bf16 (round-half-up via +0x8000, then v_perm pack)
static __device__ __forceinline__ unsigned pack2bf(float a, float b) {
    unsigned ua = __builtin_bit_cast(unsigned, a) + 0x8000u;
    unsigned ub = __builtin_bit_cast(unsigned, b) + 0x8000u;
    return __builtin_amdgcn_perm(ub, ua, 0x07060302u);
}

// ---------------- precompute: P = x@W1a + b1m, Qn[b*256+j][d] = (x@W1b)[d], pack W1c
__global__ __launch_bounds__(256) void prep_kernel(
    const float* __restrict__ x, const float* __restrict__ W1m,
    const float* __restrict__ b1m,
    float* __restrict__ P, float* __restrict__ Qn, u16* __restrict__ W1cp)
{
    if (blockIdx.x == 1024) {
        // pack W1c (rows 256..383 of W1m) into MFMA B-fragment order
        for (int idx = threadIdx.x; idx < 16384; idx += 256) {
            int e  = idx & 7;
            int ln = (idx >> 3) & 63;
            int nt = (idx >> 9) & 7;
            int kt = idx >> 12;
            int k  = kt * 32 + (ln >> 4) * 8 + e;
            int d  = nt * 16 + (ln & 15);
            W1cp[idx] = f2bf(W1m[(2 * ND + k) * ND + d]);
        }
        return;
    }
    __shared__ float xl[256];
    int t = threadIdx.x;
    int row0 = blockIdx.x * 2;
    xl[t] = x[row0 * ND + t];
    __syncthreads();
    int r = t >> 7;
    int d = t & 127;
    int row = row0 + r;
    float sp = b1m[d], sq = 0.f;
    const float* xr = &xl[r * ND];
    #pragma unroll 8
    for (int k = 0; k < ND; ++k) {
        float xv = xr[k];
        sp += xv * W1m[k * ND + d];
        sq += xv * W1m[(ND + k) * ND + d];
    }
    P[row * ND + d] = sp;
    Qn[row * ND + d] = sq;          // row-major: coalesced reads in fused kernel
}

// ---------------- fused: per-block (b,i). 16 chunks x 16 rows, 3 LDS buffers,
// depth-2 DMA pipeline, ONE barrier per chunk, exact vmcnt ledger.
__global__ __launch_bounds__(256, 5) void fused_kernel(
    const float* __restrict__ x, const float* __restrict__ edge0,
    const int* __restrict__ mask,
    const float* __restrict__ W2m, const float* __restrict__ b2m,
    const float* __restrict__ W1u, const float* __restrict__ b1u,
    const float* __restrict__ W2u, const float* __restrict__ b2u,
    const float* __restrict__ gamma, const float* __restrict__ beta,
    const float* __restrict__ P, const float* __restrict__ Qn,
    const u16* __restrict__ W1cp,
    float* __restrict__ out)
{
    __shared__ float ebuf[3][2048];   // 3 x 8KB chunk buffers (16 rows x 128 f32)
    __shared__ float ml[NN];
    __shared__ float xrow[ND];
    __shared__ float redc[4], redA[4], redB[4];

    // tail scratch carved from ebuf[1] (last main-loop read: chunk 13)
    float* aggH = &ebuf[1][0];
    float* am   = &ebuf[1][128];
    float* hu   = &ebuf[1][256];
    float* yl   = &ebuf[1][384];

    // bijective XCD swizzle: XCD k owns batch k
    const int bid  = (blockIdx.x & 7) * 256 + (blockIdx.x >> 3);
    const int b    = bid >> 8;
    const int tid  = threadIdx.x;
    const int wave = tid >> 6;
    const int lane = tid & 63;
    const int l15  = lane & 15;
    const int lg   = lane >> 4;

    const char* e0c = (const char*)(edge0 + (size_t)bid * (NN * ND));

    float mval = (float)mask[bid * NN + tid];
    ml[tid] = mval;
    if (tid < ND) xrow[tid] = x[bid * ND + tid];

    // B fragments: this wave's 2 col-tiles x 4 k-tiles (32 VGPR)
    s8v bfr[4][2];
    #pragma unroll
    for (int kt = 0; kt < 4; ++kt)
        #pragma unroll
        for (int n = 0; n < 2; ++n)
            bfr[kt][n] = *reinterpret_cast<const s8v*>(
                &W1cp[(((kt * 8) + (wave * 2 + n)) * 64 + lane) * 8]);

    const int col0 = wave * 32 + l15;
    const float pv0 = P[bid * ND + col0];
    const float pv1 = P[bid * ND + col0 + 16];
    // Qn row base for this lane: row j = c*16 + lg*4 + r, element col0 (+16)
    const float* qbase = Qn + ((size_t)b * NN + lg * 4) * ND + col0;

    // stage chunk cc (16 rows x 128 f32 = 8KB) into buffer bb: 2 DMA/wave.
    // LDS dest linear; global source carries inverse XOR swizzle (16B granular).
    auto STAGE = [&](int cc, int bb) {
        const char* cb = e0c + (size_t)cc * 8192;
        #pragma unroll
        for (int u = 0; u < 2; ++u) {
            int row  = wave * 4 + u * 2 + (lane >> 5);
            int colb = (lane & 31) * 16;
            const char* g = cb + row * 512 + (colb ^ ((row & 7) << 4));
            __builtin_amdgcn_global_load_lds(
                (GAS*)g, (LAS*)&ebuf[bb][(wave * 2 + u) * 256], 16, 0, 0);
        }
    };

    float q0v[2][4], q1v[2][4];   // 2 generations, static-indexed under unroll
    auto LOADQ = [&](int cc, int gg) {
        const float* qr = qbase + (size_t)cc * 16 * ND;
        #pragma unroll
        for (int r = 0; r < 4; ++r) {
            q0v[gg][r] = qr[r * ND];
            q1v[gg][r] = qr[r * ND + 16];
        }
    };

    float agg0 = 0.f, agg1 = 0.f;

    // zero the vmcnt ledger, then prologue issue: E0, Q0, E1
    asm volatile("s_waitcnt vmcnt(0) lgkmcnt(0)" ::: "memory");
    __builtin_amdgcn_sched_barrier(0);
    STAGE(0, 0);
    __builtin_amdgcn_sched_barrier(0);
    LOADQ(0, 0);
    __builtin_amdgcn_sched_barrier(0);
    STAGE(1, 1);
    __builtin_amdgcn_sched_barrier(0);

    #pragma unroll
    for (int c = 0; c < 16; ++c) {
        // top-of-iter queue: [E_c(2), Q_c(8), E_{c+1}(2)] (c<15) or [E_15(2), Q_15(8)]
        if (c < 15)
            asm volatile("s_waitcnt vmcnt(10) lgkmcnt(0)" ::: "memory");
        else
            asm volatile("s_waitcnt vmcnt(8) lgkmcnt(0)" ::: "memory");
        __builtin_amdgcn_s_barrier();
        __builtin_amdgcn_sched_barrier(0);
        // issue next-gen loads (buffer (c+2)%3 safe: all waves done compute c-1)
        if (c < 15) {
            LOADQ(c + 1, (c + 1) & 1);
            __builtin_amdgcn_sched_barrier(0);
            if (c < 14) {
                STAGE(c + 2, (c + 2) % 3);
                __builtin_amdgcn_sched_barrier(0);
            }
        }
        // ---- compute chunk c from ebuf[c%3]: 16 rows, this wave's 32 cols ----
        const char* bufc = (const char*)&ebuf[c % 3][0];
        const int rb  = l15 * 512;
        const int swz = (l15 & 7) << 4;
        f4 acc0 = {0.f, 0.f, 0.f, 0.f};
        f4 acc1 = {0.f, 0.f, 0.f, 0.f};
        #pragma unroll
        for (int kt = 0; kt < 4; ++kt) {
            int cbyte = kt * 128 + lg * 32;
            f4 a0 = *reinterpret_cast<const f4*>(bufc + rb + ((cbyte)      ^ swz));
            f4 a1 = *reinterpret_cast<const f4*>(bufc + rb + ((cbyte + 16) ^ swz));
            u32x4v aw;
            aw[0] = pack2bf(a0[0], a0[1]);
            aw[1] = pack2bf(a0[2], a0[3]);
            aw[2] = pack2bf(a1[0], a1[1]);
            aw[3] = pack2bf(a1[2], a1[3]);
            bf8v av = __builtin_bit_cast(bf8v, aw);
            acc0 = __builtin_amdgcn_mfma_f32_16x16x32_bf16(
                av, __builtin_bit_cast(bf8v, bfr[kt][0]), acc0, 0, 0, 0);
            acc1 = __builtin_amdgcn_mfma_f32_16x16x32_bf16(
                av, __builtin_bit_cast(bf8v, bfr[kt][1]), acc1, 0, 0, 0);
        }
        // rows j = c*16 + lg*4 + r; mask + P + Q + relu + agg
        f4 mk = *reinterpret_cast<const f4*>(&ml[c * 16 + lg * 4]);
        const int g = c & 1;
        #pragma unroll
        for (int r = 0; r < 4; ++r) {
            float h0 = fmaxf(acc0[r] + pv0 + q0v[g][r], 0.f);
            float h1 = fmaxf(acc1[r] + pv1 + q1v[g][r], 0.f);
            agg0 += mk[r] * h0;
            agg1 += mk[r] * h1;
        }
    }

    // reduce agg partials across the 4 row-groups
    agg0 += __shfl_xor(agg0, 16); agg0 += __shfl_xor(agg0, 32);
    agg1 += __shfl_xor(agg1, 16); agg1 += __shfl_xor(agg1, 32);
    if (lg == 0) {
        aggH[wave * 32 + l15]      = agg0;   // ebuf[1] carve: safe vs compute 14 (buf2) / 15 (buf0)
        aggH[wave * 32 + 16 + l15] = agg1;
    }
    // cnt = sum(mask)
    float cv = mval;
    #pragma unroll
    for (int o = 32; o > 0; o >>= 1) cv += __shfl_xor(cv, o);
    if (lane == 0) redc[wave] = cv;
    __syncthreads();

    const float cnt = redc[0] + redc[1] + redc[2] + redc[3];
    const float inv = 1.f / (cnt + 1e-6f);
    const int d  = tid & 127;
    const int hf = tid >> 7;

    // agg_msg = (aggH @ W2m + cnt*b2m) / (cnt+eps)
    {
        float s = 0.f;
        #pragma unroll 8
        for (int k = hf * 64; k < hf * 64 + 64; ++k) s += aggH[k] * W2m[k * ND + d];
        ml[tid] = s;
    }
    __syncthreads();
    if (tid < ND) am[d] = (ml[d] + ml[d + ND] + cnt * b2m[d]) * inv;
    __syncthreads();
    // hu = relu([x, agg] @ W1u + b1u)
    {
        float s = 0.f;
        const float* W = W1u + (size_t)hf * ND * ND;
        const float* v = hf ? am : xrow;
        #pragma unroll 8
        for (int k = 0; k < ND; ++k) s += v[k] * W[k * ND + d];
        ml[tid] = s;
    }
    __syncthreads();
    if (tid < ND) hu[d] = fmaxf(ml[d] + ml[d + ND] + b1u[d], 0.f);
    __syncthreads();
    // y = x + hu @ W2u + b2u
    {
        float s = 0.f;
        #pragma unroll 8
        for (int k = hf * 64; k < hf * 64 + 64; ++k) s += hu[k] * W2u[k * ND + d];
        ml[tid] = s;
    }
    __syncthreads();
    if (tid < ND) yl[d] = xrow[d] + ml[d] + ml[d + ND] + b2u[d];
    __syncthreads();
    // LayerNorm
    float yv = (tid < ND) ? yl[tid] : 0.f;
    float s1 = yv, s2 = yv * yv;
    #pragma unroll
    for (int o = 32; o > 0; o >>= 1) { s1 += __shfl_xor(s1, o); s2 += __shfl_xor(s2, o); }
    if (lane == 0) { redA[wave] = s1; redB[wave] = s2; }
    __syncthreads();
    if (tid < ND) {
        float mu  = (redA[0] + redA[1] + redA[2] + redA[3]) * (1.f / 128.f);
        float ex2 = (redB[0] + redB[1] + redB[2] + redB[3]) * (1.f / 128.f);
        float var = ex2 - mu * mu;
        float rs  = rsqrtf(var + 1e-5f);
        out[bid * ND + d] = (yl[d] - mu) * rs * gamma[d] + beta[d];
    }
}

extern "C" void kernel_launch(void* const* d_in, const int* in_sizes, int n_in,
                              void* d_out, int out_size, void* d_ws, size_t ws_size,
                              hipStream_t stream) {
    (void)in_sizes; (void)n_in; (void)out_size; (void)ws_size;
    const float* x     = (const float*)d_in[0];
    const float* edge0 = (const float*)d_in[1];
    const int*   mask  = (const int*)d_in[2];
    const float* W1m   = (const float*)d_in[3];
    const float* b1m   = (const float*)d_in[4];
    const float* W2m   = (const float*)d_in[5];
    const float* b2m   = (const float*)d_in[6];
    const float* W1u   = (const float*)d_in[7];
    const float* b1u   = (const float*)d_in[8];
    const float* W2u   = (const float*)d_in[9];
    const float* b2u   = (const float*)d_in[10];
    const float* gamma = (const float*)d_in[11];
    const float* beta  = (const float*)d_in[12];

    float* P    = (float*)d_ws;                 // 2048*128 f32 = 1 MB
    float* Qn   = P + 2048 * 128;               // 2048*128 f32 = 1 MB (row-major)
    u16*   W1cp = (u16*)(Qn + 2048 * 128);      // 16384 bf16 = 32 KB

    float* o = (float*)d_out;

    prep_kernel<<<dim3(1025), dim3(256), 0, stream>>>(x, W1m, b1m, P, Qn, W1cp);
    fused_kernel<<<dim3(2048), dim3(256), 0, stream>>>(
        x, edge0, mask, W2m, b2m, W1u, b1u, W2u, b2u, gamma, beta,
        P, Qn, W1cp, o);
}

// Round 9
// 82.112 us; speedup vs baseline: 2.7975x; 1.1642x over previous
//
#include <hip/hip_runtime.h>
#include <hip/hip_bf16.h>

typedef float    f4    __attribute__((ext_vector_type(4)));
typedef short    s8v   __attribute__((ext_vector_type(8)));
typedef __bf16   bf8v  __attribute__((ext_vector_type(8)));
typedef unsigned int u32x4v __attribute__((ext_vector_type(4)));
typedef unsigned short u16;

#define NB 8
#define NN 256
#define ND 128

static __device__ __forceinline__ u16 f2bf(float f) {
    union { float f; unsigned u; } v; v.f = f;
    unsigned r = v.u + 0x7FFF + ((v.u >> 16) & 1);   // RNE
    return (u16)(r >> 16);
}

// pack two f32 -> two bf16 (round-half-up via +0x8000, then v_perm pack)
static __device__ __forceinline__ unsigned pack2bf(float a, float b) {
    unsigned ua = __builtin_bit_cast(unsigned, a) + 0x8000u;
    unsigned ub = __builtin_bit_cast(unsigned, b) + 0x8000u;
    return __builtin_amdgcn_perm(ub, ua, 0x07060302u);
}

// ---------------- precompute: P = x@W1a + b1m, Qn[b*256+j][d] = (x@W1b)[d], pack W1c
__global__ __launch_bounds__(256) void prep_kernel(
    const float* __restrict__ x, const float* __restrict__ W1m,
    const float* __restrict__ b1m,
    float* __restrict__ P, float* __restrict__ Qn, u16* __restrict__ W1cp)
{
    if (blockIdx.x == 1024) {
        // pack W1c (rows 256..383 of W1m) into MFMA B-fragment order
        for (int idx = threadIdx.x; idx < 16384; idx += 256) {
            int e  = idx & 7;
            int ln = (idx >> 3) & 63;
            int nt = (idx >> 9) & 7;
            int kt = idx >> 12;
            int k  = kt * 32 + (ln >> 4) * 8 + e;
            int d  = nt * 16 + (ln & 15);
            W1cp[idx] = f2bf(W1m[(2 * ND + k) * ND + d]);
        }
        return;
    }
    __shared__ float xl[256];
    int t = threadIdx.x;
    int row0 = blockIdx.x * 2;
    xl[t] = x[row0 * ND + t];
    __syncthreads();
    int r = t >> 7;
    int d = t & 127;
    int row = row0 + r;
    float sp = b1m[d], sq = 0.f;
    const float* xr = &xl[r * ND];
    #pragma unroll 8
    for (int k = 0; k < ND; ++k) {
        float xv = xr[k];
        sp += xv * W1m[k * ND + d];
        sq += xv * W1m[(ND + k) * ND + d];
    }
    P[row * ND + d] = sp;
    Qn[row * ND + d] = sq;          // row-major: coalesced reads in fused kernel
}

// ---------------- fused: per-block (b,i). 16 chunks x 16 rows.
// Reg-staged bf16 staging: global f4 -> pack2bf -> ds_write_b128 (4KB bf16 chunks),
// 3 buffers, depth-2 E pipeline, ONE barrier per chunk, counted vmcnt ledger.
__global__ __launch_bounds__(256, 5) void fused_kernel(
    const float* __restrict__ x, const float* __restrict__ edge0,
    const int* __restrict__ mask,
    const float* __restrict__ W2m, const float* __restrict__ b2m,
    const float* __restrict__ W1u, const float* __restrict__ b1u,
    const float* __restrict__ W2u, const float* __restrict__ b2u,
    const float* __restrict__ gamma, const float* __restrict__ beta,
    const float* __restrict__ P, const float* __restrict__ Qn,
    const u16* __restrict__ W1cp,
    float* __restrict__ out)
{
    __shared__ float ebuf[3][1024];   // 3 x 4KB bf16 chunk buffers (16 rows x 128 bf16)
    __shared__ float ml[NN];
    __shared__ float xrow[ND];
    __shared__ float redc[4], redA[4], redB[4];

    // tail scratch carved from ebuf[1] (last read of buf1: chunk 13)
    float* aggH = &ebuf[1][0];
    float* am   = &ebuf[1][128];
    float* hu   = &ebuf[1][256];
    float* yl   = &ebuf[1][384];

    // bijective XCD swizzle: XCD k owns batch k
    const int bid  = (blockIdx.x & 7) * 256 + (blockIdx.x >> 3);
    const int b    = bid >> 8;
    const int tid  = threadIdx.x;
    const int wave = tid >> 6;
    const int lane = tid & 63;
    const int l15  = lane & 15;
    const int lg   = lane >> 4;

    const char* e0c = (const char*)(edge0 + (size_t)bid * (NN * ND));

    float mval = (float)mask[bid * NN + tid];
    ml[tid] = mval;
    if (tid < ND) xrow[tid] = x[bid * ND + tid];

    // B fragments: this wave's 2 col-tiles x 4 k-tiles (32 VGPR)
    s8v bfr[4][2];
    #pragma unroll
    for (int kt = 0; kt < 4; ++kt)
        #pragma unroll
        for (int n = 0; n < 2; ++n)
            bfr[kt][n] = *reinterpret_cast<const s8v*>(
                &W1cp[(((kt * 8) + (wave * 2 + n)) * 64 + lane) * 8]);

    const int col0 = wave * 32 + l15;
    const float pv0 = P[bid * ND + col0];
    const float pv1 = P[bid * ND + col0 + 16];
    // Qn row base for this lane: row j = c*16 + lg*4 + r, element col0 (+16)
    const float* qbase = Qn + ((size_t)b * NN + lg * 4) * ND + col0;

    // staging geometry: thread t owns 8 consecutive f32 of the chunk
    // (row = t>>4, col8 = t&15) -> one swizzled ds_write_b128 of 8 bf16.
    const int srow  = tid >> 4;
    const int swoff = srow * 256 + (((tid & 15) * 16) ^ ((srow & 7) << 4));

    // E issue: two f4 per thread, coalesced
    auto LOADE = [&](int cc, f4* er) {
        const char* cb = e0c + (size_t)cc * 8192 + tid * 32;
        er[0] = *reinterpret_cast<const f4*>(cb);
        er[1] = *reinterpret_cast<const f4*>(cb + 16);
    };
    // pack + swizzled LDS write into buffer bb
    auto WRITEE = [&](const f4* er, int bb) {
        u32x4v aw;
        aw[0] = pack2bf(er[0][0], er[0][1]);
        aw[1] = pack2bf(er[0][2], er[0][3]);
        aw[2] = pack2bf(er[1][0], er[1][1]);
        aw[3] = pack2bf(er[1][2], er[1][3]);
        *reinterpret_cast<u32x4v*>(
            reinterpret_cast<char*>(&ebuf[bb][0]) + swoff) = aw;
    };

    float agg0 = 0.f, agg1 = 0.f;
    f4 eA[2], eB[2];   // two static generations (even chunks -> eA, odd -> eB)

    // prologue: issue E0, E1; drain E0 (and all prologue VMEM); write chunk0 -> buf0
    LOADE(0, eA);
    __builtin_amdgcn_sched_barrier(0);
    LOADE(1, eB);
    __builtin_amdgcn_sched_barrier(0);
    asm volatile("s_waitcnt vmcnt(2)" ::: "memory");   // E0 + everything older
    WRITEE(eA, 0);
    asm volatile("s_waitcnt lgkmcnt(0)" ::: "memory");

    #pragma unroll
    for (int c = 0; c < 16; ++c) {
        // top barrier: chunk c's writes (done at end of iter c-1 / prologue) visible
        __builtin_amdgcn_s_barrier();
        __builtin_amdgcn_sched_barrier(0);
        // issue Q_c FIRST (so its compiler-wait leaves E_{c+2} in flight), then E_{c+2}
        float q0v[4], q1v[4];
        {
            const float* qr = qbase + (size_t)c * 16 * ND;
            #pragma unroll
            for (int r = 0; r < 4; ++r) {
                q0v[r] = qr[r * ND];
                q1v[r] = qr[r * ND + 16];
            }
        }
        __builtin_amdgcn_sched_barrier(0);
        if (c < 14) {
            if (c & 1) LOADE(c + 2, eA); else LOADE(c + 2, eB);
            __builtin_amdgcn_sched_barrier(0);
        }
        // ---- compute chunk c from bf16 buf[c%3]: 16 rows, this wave's 32 cols ----
        const char* bufc = (const char*)&ebuf[c % 3][0];
        const int rb  = l15 * 256;
        const int swz = (l15 & 7) << 4;
        f4 acc0 = {0.f, 0.f, 0.f, 0.f};
        f4 acc1 = {0.f, 0.f, 0.f, 0.f};
        #pragma unroll
        for (int kt = 0; kt < 4; ++kt) {
            s8v av = *reinterpret_cast<const s8v*>(
                bufc + rb + ((kt * 64 + lg * 16) ^ swz));
            acc0 = __builtin_amdgcn_mfma_f32_16x16x32_bf16(
                __builtin_bit_cast(bf8v, av), __builtin_bit_cast(bf8v, bfr[kt][0]), acc0, 0, 0, 0);
            acc1 = __builtin_amdgcn_mfma_f32_16x16x32_bf16(
                __builtin_bit_cast(bf8v, av), __builtin_bit_cast(bf8v, bfr[kt][1]), acc1, 0, 0, 0);
        }
        // rows j = c*16 + lg*4 + r; mask + P + Q + relu + agg
        f4 mk = *reinterpret_cast<const f4*>(&ml[c * 16 + lg * 4]);
        #pragma unroll
        for (int r = 0; r < 4; ++r) {
            float h0 = fmaxf(acc0[r] + pv0 + q0v[r], 0.f);
            float h1 = fmaxf(acc1[r] + pv1 + q1v[r], 0.f);
            agg0 += mk[r] * h0;
            agg1 += mk[r] * h1;
        }
        __builtin_amdgcn_sched_barrier(0);
        // ---- stage chunk c+1 into buf (c+1)%3 (E_{c+1} drained by Q_c's wait) ----
        if (c < 15) {
            asm volatile("s_waitcnt vmcnt(2)" ::: "memory");  // E_{c+1}; leaves E_{c+2}
            if (c & 1) WRITEE(eA, (c + 1) % 3); else WRITEE(eB, (c + 1) % 3);
            asm volatile("s_waitcnt lgkmcnt(0)" ::: "memory");
            __builtin_amdgcn_sched_barrier(0);
        }
    }

    // reduce agg partials across the 4 row-groups
    agg0 += __shfl_xor(agg0, 16); agg0 += __shfl_xor(agg0, 32);
    agg1 += __shfl_xor(agg1, 16); agg1 += __shfl_xor(agg1, 32);
    // cnt = sum(mask)
    float cv = mval;
    #pragma unroll
    for (int o = 32; o > 0; o >>= 1) cv += __shfl_xor(cv, o);
    if (lane == 0) redc[wave] = cv;
    __syncthreads();   // main loop fully done; tail carve of ebuf[1] now safe
    if (lg == 0) {
        aggH[wave * 32 + l15]      = agg0;
        aggH[wave * 32 + 16 + l15] = agg1;
    }
    __syncthreads();

    const float cnt = redc[0] + redc[1] + redc[2] + redc[3];
    const float inv = 1.f / (cnt + 1e-6f);
    const int d  = tid & 127;
    const int hf = tid >> 7;

    // agg_msg = (aggH @ W2m + cnt*b2m) / (cnt+eps)
    {
        float s = 0.f;
        #pragma unroll 8
        for (int k = hf * 64; k < hf * 64 + 64; ++k) s += aggH[k] * W2m[k * ND + d];
        ml[tid] = s;
    }
    __syncthreads();
    if (tid < ND) am[d] = (ml[d] + ml[d + ND] + cnt * b2m[d]) * inv;
    __syncthreads();
    // hu = relu([x, agg] @ W1u + b1u)
    {
        float s = 0.f;
        const float* W = W1u + (size_t)hf * ND * ND;
        const float* v = hf ? am : xrow;
        #pragma unroll 8
        for (int k = 0; k < ND; ++k) s += v[k] * W[k * ND + d];
        ml[tid] = s;
    }
    __syncthreads();
    if (tid < ND) hu[d] = fmaxf(ml[d] + ml[d + ND] + b1u[d], 0.f);
    __syncthreads();
    // y = x + hu @ W2u + b2u
    {
        float s = 0.f;
        #pragma unroll 8
        for (int k = hf * 64; k < hf * 64 + 64; ++k) s += hu[k] * W2u[k * ND + d];
        ml[tid] = s;
    }
    __syncthreads();
    if (tid < ND) yl[d] = xrow[d] + ml[d] + ml[d + ND] + b2u[d];
    __syncthreads();
    // LayerNorm
    float yv = (tid < ND) ? yl[tid] : 0.f;
    float s1 = yv, s2 = yv * yv;
    #pragma unroll
    for (int o = 32; o > 0; o >>= 1) { s1 += __shfl_xor(s1, o); s2 += __shfl_xor(s2, o); }
    if (lane == 0) { redA[wave] = s1; redB[wave] = s2; }
    __syncthreads();
    if (tid < ND) {
        float mu  = (redA[0] + redA[1] + redA[2] + redA[3]) * (1.f / 128.f);
        float ex2 = (redB[0] + redB[1] + redB[2] + redB[3]) * (1.f / 128.f);
        float var = ex2 - mu * mu;
        float rs  = rsqrtf(var + 1e-5f);
        out[bid * ND + d] = (yl[d] - mu) * rs * gamma[d] + beta[d];
    }
}

extern "C" void kernel_launch(void* const* d_in, const int* in_sizes, int n_in,
                              void* d_out, int out_size, void* d_ws, size_t ws_size,
                              hipStream_t stream) {
    (void)in_sizes; (void)n_in; (void)out_size; (void)ws_size;
    const float* x     = (const float*)d_in[0];
    const float* edge0 = (const float*)d_in[1];
    const int*   mask  = (const int*)d_in[2];
    const float* W1m   = (const float*)d_in[3];
    const float* b1m   = (const float*)d_in[4];
    const float* W2m   = (const float*)d_in[5];
    const float* b2m   = (const float*)d_in[6];
    const float* W1u   = (const float*)d_in[7];
    const float* b1u   = (const float*)d_in[8];
    const float* W2u   = (const float*)d_in[9];
    const float* b2u   = (const float*)d_in[10];
    const float* gamma = (const float*)d_in[11];
    const float* beta  = (const float*)d_in[12];

    float* P    = (float*)d_ws;                 // 2048*128 f32 = 1 MB
    float* Qn   = P + 2048 * 128;               // 2048*128 f32 = 1 MB (row-major)
    u16*   W1cp = (u16*)(Qn + 2048 * 128);      // 16384 bf16 = 32 KB

    float* o = (float*)d_out;

    prep_kernel<<<dim3(1025), dim3(256), 0, stream>>>(x, W1m, b1m, P, Qn, W1cp);
    fused_kernel<<<dim3(2048), dim3(256), 0, stream>>>(
        x, edge0, mask, W2m, b2m, W1u, b1u, W2u, b2u, gamma, beta,
        P, Qn, W1cp, o);
}